// Round 11
// baseline (860.194 us; speedup 1.0000x reference)
//
#include <hip/hip_runtime.h>

typedef __attribute__((ext_vector_type(4))) int   int4v;
typedef __attribute__((ext_vector_type(4))) float float4v;

// XOR swizzle of the 16B slot within a 64B K-row (round-0 proven layout).
__device__ __forceinline__ int swz(int row, int slot) {
    return slot ^ ((row ^ (row >> 2)) & 3);
}

// Real-kernel quant (r3-validated: recip fast path + rare exact-div tie fixup).
__device__ __forceinline__ int4v quant4(float4v v, float lo, float up,
                                        float scale, float inv) {
    float t0 = fminf(fmaxf(v[0], lo), up) - lo;
    float t1 = fminf(fmaxf(v[1], lo), up) - lo;
    float t2 = fminf(fmaxf(v[2], lo), up) - lo;
    float t3 = fminf(fmaxf(v[3], lo), up) - lo;
    float m0 = t0 * inv, m1 = t1 * inv, m2 = t2 * inv, m3 = t3 * inv;
    float r0 = rintf(m0), r1 = rintf(m1), r2 = rintf(m2), r3 = rintf(m3);
    float d0 = fabsf(fabsf(m0 - r0) - 0.5f);
    float d1 = fabsf(fabsf(m1 - r1) - 0.5f);
    float d2 = fabsf(fabsf(m2 - r2) - 0.5f);
    float d3 = fabsf(fabsf(m3 - r3) - 0.5f);
    if (fminf(fminf(d0, d1), fminf(d2, d3)) < 1e-4f) {
        r0 = rintf(t0 / scale); r1 = rintf(t1 / scale);
        r2 = rintf(t2 / scale); r3 = rintf(t3 / scale);
    }
    int4v q = {(int)r0, (int)r1, (int)r2, (int)r3};
    return q;
}

// Probe quant: branchless pure div -> data-independent probe timing.
__device__ __forceinline__ int4v quant4b(float4v v, float lo, float up, float sc) {
    int4v q;
    #pragma unroll
    for (int i = 0; i < 4; ++i) {
        float xc = fminf(fmaxf(v[i], lo), up);
        q[i] = (int)rintf((xc - lo) / sc);
    }
    return q;
}

__device__ __forceinline__ unsigned bsum(int p) {
    return ((unsigned)p * 0x01010101u) >> 24;
}

// ---------------- real kernel: round-3 verbatim (98.6 us, absmax 0.875) ----
__global__ __launch_bounds__(256, 4) void qmm_kernel(
    const float* __restrict__ A, const float* __restrict__ B,
    const float* __restrict__ aLo, const float* __restrict__ aUp,
    const float* __restrict__ bLo, const float* __restrict__ bUp,
    float* __restrict__ Out)
{
    __shared__ int   qA[256 * 16];
    __shared__ int   qB[256 * 16];
    __shared__ float RAf[256];
    __shared__ float CBf[256];

    const int tid = threadIdx.x;
    const int b   = blockIdx.x;

    const float lA = aLo[0], uA = aUp[0];
    const float lB = bLo[0], uB = bUp[0];
    const float sA  = (uA - lA) / 15.0f;
    const float sB  = (uB - lB) / 15.0f;
    const float iA  = 1.0f / sA;
    const float iB  = 1.0f / sB;
    const float sAB = sA * sB;

    const float4v* A4 = (const float4v*)(A + (size_t)b * 256 * 64);
    const float4v* B4 = (const float4v*)(B + (size_t)b * 64 * 256);
    float* outb = Out + (size_t)b * 256 * 256;

    #pragma unroll
    for (int it = 0; it < 16; ++it) {
        int f = it * 256 + tid;
        float4v v = A4[f];
        int4v q = quant4(v, lA, uA, sA, iA);
        int p  = q[0] | (q[1] << 8) | (q[2] << 16) | (q[3] << 24);
        int row = f >> 4, chunk = f & 15;
        qA[row * 16 + swz(row, chunk >> 2) * 4 + (chunk & 3)] = p;
    }

    const int u  = tid & 63;
    const int kg = tid >> 6;
    #pragma unroll
    for (int kb = 0; kb < 4; ++kb) {
        int k0 = kb * 16 + kg * 4;
        int4v q0 = quant4(B4[(size_t)(k0 + 0) * 64 + u], lB, uB, sB, iB);
        int4v q1 = quant4(B4[(size_t)(k0 + 1) * 64 + u], lB, uB, sB, iB);
        int4v q2 = quant4(B4[(size_t)(k0 + 2) * 64 + u], lB, uB, sB, iB);
        int4v q3 = quant4(B4[(size_t)(k0 + 3) * 64 + u], lB, uB, sB, iB);
        #pragma unroll
        for (int c = 0; c < 4; ++c) {
            int col = u * 4 + c;
            int p = q0[c] | (q1[c] << 8) | (q2[c] << 16) | (q3[c] << 24);
            qB[col * 16 + swz(col, kb) * 4 + kg] = p;
        }
    }

    __syncthreads();

    {
        unsigned sa = 0, sb = 0;
        #pragma unroll
        for (int j = 0; j < 16; ++j) {
            sa += bsum((unsigned)qA[tid * 16 + swz(tid, j >> 2) * 4 + (j & 3)]);
            sb += bsum((unsigned)qB[tid * 16 + swz(tid, j >> 2) * 4 + (j & 3)]);
        }
        float c32 = 32.0f * lA * lB;
        RAf[tid] = sA * lB * (float)sa + c32;
        CBf[tid] = lA * sB * (float)sb + c32;
    }
    __syncthreads();

    const int wave = tid >> 6, lane = tid & 63;
    const int lr = lane & 15;
    const int lk = lane >> 4;

    int4v afrag[4];
    #pragma unroll
    for (int rt = 0; rt < 4; ++rt) {
        int row = wave * 64 + rt * 16 + lr;
        afrag[rt] = *(const int4v*)&qA[row * 16 + swz(row, lk) * 4];
    }

    #pragma unroll 4
    for (int ct = 0; ct < 16; ++ct) {
        int col = ct * 16 + lr;
        int4v bfrag = *(const int4v*)&qB[col * 16 + swz(col, lk) * 4];
        float cb = CBf[col];
        #pragma unroll
        for (int rt = 0; rt < 4; ++rt) {
            int4v acc = {0, 0, 0, 0};
            acc = __builtin_amdgcn_mfma_i32_16x16x64_i8(afrag[rt], bfrag, acc, 0, 0, 0);
            int orow = wave * 64 + rt * 16 + lk * 4;
            #pragma unroll
            for (int r = 0; r < 4; ++r) {
                outb[(size_t)(orow + r) * 256 + col] =
                    sAB * (float)acc[r] + RAf[orow + r] + cb;
            }
        }
    }
}

// ================= probe building blocks (exact qmm structure) ==============

__device__ __forceinline__ void p_stageA(const float4v* A4, int* qA, int tid,
                                         float lo, float up, float sc) {
    float4v va[16];
    #pragma unroll
    for (int it = 0; it < 16; ++it) va[it] = A4[it * 256 + tid];
    #pragma unroll
    for (int it = 0; it < 16; ++it) {
        int f = it * 256 + tid;
        int4v q = quant4b(va[it], lo, up, sc);
        int p = q[0] | (q[1] << 8) | (q[2] << 16) | (q[3] << 24);
        int row = f >> 4, chunk = f & 15;
        qA[row * 16 + swz(row, chunk >> 2) * 4 + (chunk & 3)] = p;
    }
}

__device__ __forceinline__ void p_stageB(const float4v* B4, int* qB, int tid,
                                         float lo, float up, float sc) {
    const int u = tid & 63, kg = tid >> 6;
    float4v vb[16];
    #pragma unroll
    for (int kb = 0; kb < 4; ++kb)
        #pragma unroll
        for (int r = 0; r < 4; ++r)
            vb[kb * 4 + r] = B4[(size_t)(kb * 16 + kg * 4 + r) * 64 + u];
    #pragma unroll
    for (int kb = 0; kb < 4; ++kb) {
        int4v q0 = quant4b(vb[kb * 4 + 0], lo, up, sc);
        int4v q1 = quant4b(vb[kb * 4 + 1], lo, up, sc);
        int4v q2 = quant4b(vb[kb * 4 + 2], lo, up, sc);
        int4v q3 = quant4b(vb[kb * 4 + 3], lo, up, sc);
        #pragma unroll
        for (int c = 0; c < 4; ++c) {
            int col = u * 4 + c;
            int p = q0[c] | (q1[c] << 8) | (q2[c] << 16) | (q3[c] << 24);
            qB[col * 16 + swz(col, kb) * 4 + kg] = p;
        }
    }
}

// quant+pack from pre-loaded regs (for the pipelined variant)
__device__ __forceinline__ void p_quantA(const float4v va[16], int* qA, int tid,
                                         float lo, float up, float sc) {
    #pragma unroll
    for (int it = 0; it < 16; ++it) {
        int f = it * 256 + tid;
        int4v q = quant4b(va[it], lo, up, sc);
        int p = q[0] | (q[1] << 8) | (q[2] << 16) | (q[3] << 24);
        int row = f >> 4, chunk = f & 15;
        qA[row * 16 + swz(row, chunk >> 2) * 4 + (chunk & 3)] = p;
    }
}
__device__ __forceinline__ void p_quantB(const float4v vb[16], int* qB, int tid,
                                         float lo, float up, float sc) {
    const int u = tid & 63, kg = tid >> 6;
    #pragma unroll
    for (int kb = 0; kb < 4; ++kb) {
        int4v q0 = quant4b(vb[kb * 4 + 0], lo, up, sc);
        int4v q1 = quant4b(vb[kb * 4 + 1], lo, up, sc);
        int4v q2 = quant4b(vb[kb * 4 + 2], lo, up, sc);
        int4v q3 = quant4b(vb[kb * 4 + 3], lo, up, sc);
        #pragma unroll
        for (int c = 0; c < 4; ++c) {
            int col = u * 4 + c;
            int p = q0[c] | (q1[c] << 8) | (q2[c] << 16) | (q3[c] << 24);
            qB[col * 16 + swz(col, kb) * 4 + kg] = p;
        }
    }
}

__device__ __forceinline__ void p_sums(const int* qA, const int* qB,
                                       float* RAf, float* CBf, int tid, float sc) {
    unsigned sa = 0, sb = 0;
    #pragma unroll
    for (int j = 0; j < 16; ++j) {
        sa += bsum((unsigned)qA[tid * 16 + swz(tid, j >> 2) * 4 + (j & 3)]);
        sb += bsum((unsigned)qB[tid * 16 + swz(tid, j >> 2) * 4 + (j & 3)]);
    }
    const float lo = -2.5f;
    float c32 = 32.0f * lo * lo;
    RAf[tid] = sc * lo * (float)sa + c32;
    CBf[tid] = lo * sc * (float)sb + c32;
}

__device__ __forceinline__ void p_epilogue(const int* qA, const int* qB,
                                           const float* RAf, const float* CBf,
                                           float* outb, float sAB, int tid) {
    const int wave = tid >> 6, lane = tid & 63;
    const int lr = lane & 15, lk = lane >> 4;
    int4v afrag[4];
    #pragma unroll
    for (int rt = 0; rt < 4; ++rt) {
        int row = wave * 64 + rt * 16 + lr;
        afrag[rt] = *(const int4v*)&qA[row * 16 + swz(row, lk) * 4];
    }
    #pragma unroll 4
    for (int ct = 0; ct < 16; ++ct) {
        int col = ct * 16 + lr;
        int4v bfrag = *(const int4v*)&qB[col * 16 + swz(col, lk) * 4];
        float cb = CBf[col];
        #pragma unroll
        for (int rt = 0; rt < 4; ++rt) {
            int4v acc = {0, 0, 0, 0};
            acc = __builtin_amdgcn_mfma_i32_16x16x64_i8(afrag[rt], bfrag, acc, 0, 0, 0);
            int orow = wave * 64 + rt * 16 + lk * 4;
            #pragma unroll
            for (int r = 0; r < 4; ++r)
                outb[(size_t)(orow + r) * 256 + col] =
                    sAB * (float)acc[r] + RAf[orow + r] + cb;
        }
    }
}

// ---- V0: qmm x2 at (256,4) — counter baseline for the real kernel ----------
__global__ __launch_bounds__(256, 4) void probe_v0(const float* __restrict__ in,
                                                   float* __restrict__ outw) {
    __shared__ int   qA[4096], qB[4096];
    __shared__ float RAf[256], CBf[256];
    const int tid = threadIdx.x;
    const float lo = -2.5f, up = 2.5f, sc = (up - lo) / 15.0f, sAB = sc * sc;
    for (int i = 0; i < 2; ++i) {
        size_t g = (size_t)blockIdx.x * 2 + i;
        const float* src = in + g * 32768;
        p_stageA((const float4v*)src, qA, tid, lo, up, sc);
        p_stageB((const float4v*)(src + 16384), qB, tid, lo, up, sc);
        __syncthreads();
        p_sums(qA, qB, RAf, CBf, tid, sc);
        __syncthreads();
        p_epilogue(qA, qB, RAf, CBf, outw + g * 65536, sAB, tid);
        __syncthreads();
    }
}

// ---- V2: identical code at (256,2) — isolates the occupancy variable ------
__global__ __launch_bounds__(256, 2) void probe_v2(const float* __restrict__ in,
                                                   float* __restrict__ outw) {
    __shared__ int   qA[4096], qB[4096];
    __shared__ float RAf[256], CBf[256];
    const int tid = threadIdx.x;
    const float lo = -2.5f, up = 2.5f, sc = (up - lo) / 15.0f, sAB = sc * sc;
    for (int i = 0; i < 2; ++i) {
        size_t g = (size_t)blockIdx.x * 2 + i;
        const float* src = in + g * 32768;
        p_stageA((const float4v*)src, qA, tid, lo, up, sc);
        p_stageB((const float4v*)(src + 16384), qB, tid, lo, up, sc);
        __syncthreads();
        p_sums(qA, qB, RAf, CBf, tid, sc);
        __syncthreads();
        p_epilogue(qA, qB, RAf, CBf, outw + g * 65536, sAB, tid);
        __syncthreads();
    }
}

// ---- V1: (256,2) + 2-batch pipeline: batch-1 loads issued BEFORE batch-0
//      stores -> read/store HBM traffic overlapped within the block ----------
__global__ __launch_bounds__(256, 2) void probe_v1(const float* __restrict__ in,
                                                   float* __restrict__ outw) {
    __shared__ int   qA[4096], qB[4096];
    __shared__ float RAf[256], CBf[256];
    const int tid = threadIdx.x;
    const int u = tid & 63, kg = tid >> 6;
    const float lo = -2.5f, up = 2.5f, sc = (up - lo) / 15.0f, sAB = sc * sc;
    size_t g0 = (size_t)blockIdx.x * 2, g1 = g0 + 1;
    const float* s0 = in + g0 * 32768;
    const float* s1 = in + g1 * 32768;

    // batch 0: stage (scoped regs), sums
    p_stageA((const float4v*)s0, qA, tid, lo, up, sc);
    p_stageB((const float4v*)(s0 + 16384), qB, tid, lo, up, sc);
    __syncthreads();
    p_sums(qA, qB, RAf, CBf, tid, sc);
    __syncthreads();

    // issue batch-1 loads NOW (32 x dwordx4 in flight across the epilogue)
    float4v wa[16], wb[16];
    #pragma unroll
    for (int it = 0; it < 16; ++it)
        wa[it] = ((const float4v*)s1)[it * 256 + tid];
    #pragma unroll
    for (int kb = 0; kb < 4; ++kb)
        #pragma unroll
        for (int r = 0; r < 4; ++r)
            wb[kb * 4 + r] = ((const float4v*)(s1 + 16384))[(size_t)(kb * 16 + kg * 4 + r) * 64 + u];
    __builtin_amdgcn_sched_barrier(0);   // pin: loads issued before epilogue

    p_epilogue(qA, qB, RAf, CBf, outw + g0 * 65536, sAB, tid);
    __syncthreads();

    // batch 1: quant from regs, sums, epilogue
    p_quantA(wa, qA, tid, lo, up, sc);
    p_quantB(wb, qB, tid, lo, up, sc);
    __syncthreads();
    p_sums(qA, qB, RAf, CBf, tid, sc);
    __syncthreads();
    p_epilogue(qA, qB, RAf, CBf, outw + g1 * 65536, sAB, tid);
}

extern "C" void kernel_launch(void* const* d_in, const int* in_sizes, int n_in,
                              void* d_out, int out_size, void* d_ws, size_t ws_size,
                              hipStream_t stream) {
    const float* A   = (const float*)d_in[0];
    const float* B   = (const float*)d_in[1];
    const float* aLo = (const float*)d_in[2];
    const float* aUp = (const float*)d_in[3];
    const float* bLo = (const float*)d_in[4];
    const float* bUp = (const float*)d_in[5];
    float* Out = (float*)d_out;

    int batches = in_sizes[0] / (256 * 64);   // 128*8 = 1024
    qmm_kernel<<<batches, 256, 0, stream>>>(A, B, aLo, aUp, bLo, bUp, Out);

    // ---- diagnostic probes: 2048 virtual batches each (~200us -> top-5) ----
    if (ws_size >= ((size_t)1 << 30)) {
        float* ws = (float*)d_ws;
        const float* I0 = ws;                    // [0, 256 MiB)
        const float* I1 = ws + 67108864;         // [256 MiB, 512 MiB)
        float*       W  = ws + 134217728;        // [512 MiB, 1 GiB)
        probe_v0<<<1024, 256, 0, stream>>>(I0, W);
        probe_v2<<<1024, 256, 0, stream>>>(I1, ws);   // out over [0,512MiB)
        probe_v1<<<1024, 256, 0, stream>>>(I0, W);
    }
}

// Round 12
// 303.054 us; speedup vs baseline: 2.8384x; 2.8384x over previous
//
#include <hip/hip_runtime.h>

typedef __attribute__((ext_vector_type(4))) int   int4v;
typedef __attribute__((ext_vector_type(4))) float float4v;

// XOR swizzle of the 16B slot within a 64B K-row (round-0 proven layout).
__device__ __forceinline__ int swz(int row, int slot) {
    return slot ^ ((row ^ (row >> 2)) & 3);
}

// r3-validated quant: reciprocal fast path + rare exact-div tie fixup (bit-exact).
__device__ __forceinline__ int4v quant4(float4v v, float lo, float up,
                                        float scale, float inv) {
    float t0 = fminf(fmaxf(v[0], lo), up) - lo;
    float t1 = fminf(fmaxf(v[1], lo), up) - lo;
    float t2 = fminf(fmaxf(v[2], lo), up) - lo;
    float t3 = fminf(fmaxf(v[3], lo), up) - lo;
    float m0 = t0 * inv, m1 = t1 * inv, m2 = t2 * inv, m3 = t3 * inv;
    float r0 = rintf(m0), r1 = rintf(m1), r2 = rintf(m2), r3 = rintf(m3);
    float d0 = fabsf(fabsf(m0 - r0) - 0.5f);
    float d1 = fabsf(fabsf(m1 - r1) - 0.5f);
    float d2 = fabsf(fabsf(m2 - r2) - 0.5f);
    float d3 = fabsf(fabsf(m3 - r3) - 0.5f);
    if (fminf(fminf(d0, d1), fminf(d2, d3)) < 1e-4f) {
        r0 = rintf(t0 / scale); r1 = rintf(t1 / scale);
        r2 = rintf(t2 / scale); r3 = rintf(t3 / scale);
    }
    int4v q = {(int)r0, (int)r1, (int)r2, (int)r3};
    return q;
}

__device__ __forceinline__ unsigned bsum(int p) {        // sum of 4 bytes (<=15 each)
    return ((unsigned)p * 0x01010101u) >> 24;
}

// Quarter-batch kernel: block q -> quarter w = q / nb (SLOW dim: gen 0 pulls all
// of B through L3 once; gens 1-3 re-read B from L3), batch b = q % nb.
// Block stages 64 A-rows + full B, computes 64x256 outputs. 4 generations of
// blocks -> device-level read/write phase mixing.
__global__ __launch_bounds__(256, 4) void qmm_q_kernel(
    const float* __restrict__ A, const float* __restrict__ B,
    const float* __restrict__ aLo, const float* __restrict__ aUp,
    const float* __restrict__ bLo, const float* __restrict__ bUp,
    float* __restrict__ Out, int nb)
{
    __shared__ int   qA[64 * 16];    // 64 rows x 64 k (i8, 16B slots, swizzled)
    __shared__ int   qB[256 * 16];   // B^T: 256 cols x 64 k
    __shared__ float RAf[64];
    __shared__ float CBf[256];

    const int tid = threadIdx.x;
    const int q   = blockIdx.x;
    const int b   = q % nb;
    const int w   = q / nb;          // quarter 0..3

    const float lA = aLo[0], uA = aUp[0];
    const float lB = bLo[0], uB = bUp[0];
    const float sA  = (uA - lA) / 15.0f;
    const float sB  = (uB - lB) / 15.0f;
    const float iA  = 1.0f / sA;
    const float iB  = 1.0f / sB;
    const float sAB = sA * sB;

    const float4v* A4 = (const float4v*)(A + (size_t)b * 16384 + (size_t)w * 4096);
    const float4v* B4 = (const float4v*)(B + (size_t)b * 16384);
    float* outq = Out + (size_t)b * 65536 + (size_t)w * 16384;

    // ---- stage A quarter: 64 rows, dense coalesced float4 loads ----
    #pragma unroll
    for (int it = 0; it < 4; ++it) {
        int f = it * 256 + tid;            // float4 idx 0..1023
        float4v v = A4[f];
        int4v qq = quant4(v, lA, uA, sA, iA);
        int p  = qq[0] | (qq[1] << 8) | (qq[2] << 16) | (qq[3] << 24);
        int row = f >> 4, chunk = f & 15;  // row 0..63
        qA[row * 16 + swz(row, chunk >> 2) * 4 + (chunk & 3)] = p;
    }

    // ---- stage B full (r3 verbatim): transpose in regs ----
    const int u  = tid & 63;
    const int kg = tid >> 6;
    #pragma unroll
    for (int kb = 0; kb < 4; ++kb) {
        int k0 = kb * 16 + kg * 4;
        int4v q0 = quant4(B4[(size_t)(k0 + 0) * 64 + u], lB, uB, sB, iB);
        int4v q1 = quant4(B4[(size_t)(k0 + 1) * 64 + u], lB, uB, sB, iB);
        int4v q2 = quant4(B4[(size_t)(k0 + 2) * 64 + u], lB, uB, sB, iB);
        int4v q3 = quant4(B4[(size_t)(k0 + 3) * 64 + u], lB, uB, sB, iB);
        #pragma unroll
        for (int c = 0; c < 4; ++c) {
            int col = u * 4 + c;
            int p = q0[c] | (q1[c] << 8) | (q2[c] << 16) | (q3[c] << 24);
            qB[col * 16 + swz(col, kb) * 4 + kg] = p;
        }
    }

    __syncthreads();

    // ---- col sums (all threads), row sums (tid < 64) ----
    {
        const float c32 = 32.0f * lA * lB;
        unsigned sb = 0;
        #pragma unroll
        for (int j = 0; j < 16; ++j)
            sb += bsum((unsigned)qB[tid * 16 + swz(tid, j >> 2) * 4 + (j & 3)]);
        CBf[tid] = lA * sB * (float)sb + c32;
        if (tid < 64) {
            unsigned sa = 0;
            #pragma unroll
            for (int j = 0; j < 16; ++j)
                sa += bsum((unsigned)qA[tid * 16 + swz(tid, j >> 2) * 4 + (j & 3)]);
            RAf[tid] = sA * lB * (float)sa + c32;
        }
    }
    __syncthreads();

    // ---- compute: wave owns 16 rows x 256 cols; r3-proven epilogue ----
    const int wave = tid >> 6, lane = tid & 63;
    const int lr = lane & 15, lk = lane >> 4;

    const int arow = wave * 16 + lr;
    int4v afrag = *(const int4v*)&qA[arow * 16 + swz(arow, lk) * 4];
    const int orow = wave * 16 + lk * 4;
    float ra[4] = {RAf[orow], RAf[orow + 1], RAf[orow + 2], RAf[orow + 3]};

    #pragma unroll 4
    for (int ct = 0; ct < 16; ++ct) {
        int col = ct * 16 + lr;
        int4v bfrag = *(const int4v*)&qB[col * 16 + swz(col, lk) * 4];
        float cb = CBf[col];
        int4v acc = {0, 0, 0, 0};
        acc = __builtin_amdgcn_mfma_i32_16x16x64_i8(afrag, bfrag, acc, 0, 0, 0);
        #pragma unroll
        for (int r = 0; r < 4; ++r) {
            outq[(size_t)(orow + r) * 256 + col] =
                sAB * (float)acc[r] + ra[r] + cb;
        }
    }
}

// ---- mixed-stream ceiling probe: per block read 128KB then write 256KB ----
// 2560 blocks = 320MB read + 640MB written, ~10 generations -> top-5 visible.
__global__ __launch_bounds__(256) void mprobe_kernel(const float4v* __restrict__ src,
                                                     float4v* __restrict__ dst)
{
    const int tid = threadIdx.x;
    const float4v* s = src + (size_t)blockIdx.x * 8192;
    float4v acc = {0.f, 0.f, 0.f, 0.f};
    #pragma unroll 8
    for (int i = 0; i < 32; ++i)
        acc += s[(size_t)i * 256 + tid];
    float4v* d = dst + (size_t)blockIdx.x * 16384;
    #pragma unroll 8
    for (int i = 0; i < 64; ++i) {
        float4v o = acc;
        o[0] += (float)i;
        d[(size_t)i * 256 + tid] = o;
    }
}

extern "C" void kernel_launch(void* const* d_in, const int* in_sizes, int n_in,
                              void* d_out, int out_size, void* d_ws, size_t ws_size,
                              hipStream_t stream) {
    const float* A   = (const float*)d_in[0];
    const float* B   = (const float*)d_in[1];
    const float* aLo = (const float*)d_in[2];
    const float* aUp = (const float*)d_in[3];
    const float* bLo = (const float*)d_in[4];
    const float* bUp = (const float*)d_in[5];
    float* Out = (float*)d_out;

    int batches = in_sizes[0] / (256 * 64);   // 128*8 = 1024
    qmm_q_kernel<<<batches * 4, 256, 0, stream>>>(A, B, aLo, aUp, bLo, bUp,
                                                  Out, batches);

    // ---- mixed-stream ceiling probe (1:2 R/W mix, our exact shape) ----
    if (ws_size >= ((size_t)1 << 30)) {
        const float4v* src = (const float4v*)d_ws;            // [0, 320MB)
        float4v* dst = (float4v*)d_ws + 20971520;             // [320MB, 960MB)
        mprobe_kernel<<<2560, 256, 0, stream>>>(src, dst);
    }
}